// Round 16
// baseline (49.300 us; speedup 1.0000x reference)
//
#include <hip/hip_runtime.h>
#include <hip/hip_bf16.h>
#include <stdint.h>
#include <math.h>

#define D     256
#define NTOT  8192
#define NSRC  4096
#define NT    64                  // 64 tiles of 128 rows
#define NTRI  (NT * (NT + 1) / 2) // 2080 upper-tri tiles
#define PREPB 256                 // prep blocks (32 rows each)

using f32x4 = __attribute__((ext_vector_type(4))) float;
using f32x2 = __attribute__((ext_vector_type(2))) float;

#define GLB_AS __attribute__((address_space(1)))
#define LDS_AS __attribute__((address_space(3)))

#if __has_builtin(__builtin_amdgcn_exp2f)
#define EXP2F __builtin_amdgcn_exp2f
#else
#define EXP2F exp2f
#endif

// ---- manual OCP e4m3 converters (RNE, FTZ below 2^-7, clamp 448) ----
__device__ inline unsigned char f32_to_e4m3(float v) {
  uint32_t u = __float_as_uint(v);
  uint32_t s = (u >> 24) & 0x80u;
  uint32_t m = u & 0x7FFFFFFFu;
  if (m <= 0x3C000000u) return (unsigned char)s;            // |v| <= 2^-7 -> 0
  if (m <  0x3C800000u) return (unsigned char)(s | 0x08u);  // -> min normal 2^-6
  if (m >= 0x43F00000u) return (unsigned char)(s | 0x7Eu);  // clamp to 448
  uint32_t r = m + 0x0007FFFFu + ((m >> 20) & 1u);          // RNE to 3 mant bits
  uint32_t e = (r >> 23) - 127u + 7u;                       // 1..15
  return (unsigned char)(s | (e << 3) | ((r >> 20) & 7u));
}
__device__ inline float e4m3_to_f32(unsigned char q) {
  uint32_t s = ((uint32_t)(q & 0x80u)) << 24;
  uint32_t em = q & 0x7Fu;
  if (em == 0) return __uint_as_float(s);                   // we never emit denormals
  uint32_t e = (em >> 3) + 120u;                            // -7 + 127
  return __uint_as_float(s | (e << 23) | ((em & 7u) << 20));
}

// workspace layout (bytes) — every region fully written before read each
// launch (no atomics, no fences, no counters) => poison-safe, deterministic.
#define OFF_XB   ((size_t)0)                        // 2 MB fp8 X
#define OFF_SQ   ((size_t)NTOT * D)                 // 8192 f32 row sq-norms
#define OFF_CP   (OFF_SQ + (size_t)NTOT * 4)        // colsum parts [PREPB][256]
#define OFF_SP   (OFF_CP + (size_t)PREPB * 256 * 4) // sq-sum parts [PREPB]
#define OFF_CF   (OFF_SP + (size_t)PREPB * 4)       // 1 f32 coeff (c4)
#define OFF_PT   (OFF_CF + 32)                      // per-tile partials [NTRI]
#define OFF_END  (OFF_PT + (size_t)NTRI * 4)

// ---- prep: f32 -> fp8 roundtrip, row sq-norms, per-block col/sq partials ----
__global__ __launch_bounds__(256) void prep_kernel(
    const float* __restrict__ src, const float* __restrict__ tgt,
    unsigned char* __restrict__ xb, float* __restrict__ sq,
    float* __restrict__ colpart, float* __restrict__ sqpart)
{
  __shared__ float scol4[4][256];
  __shared__ float sSl[4];
  const int tid = threadIdx.x, wave = tid >> 6, lane = tid & 63;
  const int row0 = blockIdx.x * 32 + wave * 8;     // blocks never straddle sides
  const float* p0 = (row0 < NSRC) ? (src + (size_t)row0 * D)
                                  : (tgt + (size_t)(row0 - NSRC) * D);
  float c0 = 0.f, c1 = 0.f, c2 = 0.f, c3 = 0.f, swave = 0.f;
  for (int rr = 0; rr < 8; ++rr) {
    const int row = row0 + rr;
    const float4 v = reinterpret_cast<const float4*>(p0 + (size_t)rr * D)[lane];
    uchar4 h;
    h.x = f32_to_e4m3(v.x); h.y = f32_to_e4m3(v.y);
    h.z = f32_to_e4m3(v.z); h.w = f32_to_e4m3(v.w);
    reinterpret_cast<uchar4*>(xb + (size_t)row * D)[lane] = h;
    const float f0 = e4m3_to_f32(h.x), f1 = e4m3_to_f32(h.y),
                f2 = e4m3_to_f32(h.z), f3 = e4m3_to_f32(h.w);
    c0 += f0; c1 += f1; c2 += f2; c3 += f3;
    float s = f0 * f0 + f1 * f1 + f2 * f2 + f3 * f3;
    #pragma unroll
    for (int off = 32; off > 0; off >>= 1) s += __shfl_down(s, off);
    if (lane == 0) { sq[row] = s; swave += s; }
  }
  scol4[wave][lane * 4 + 0] = c0;
  scol4[wave][lane * 4 + 1] = c1;
  scol4[wave][lane * 4 + 2] = c2;
  scol4[wave][lane * 4 + 3] = c3;
  if (lane == 0) sSl[wave] = swave;
  __syncthreads();
  colpart[blockIdx.x * 256 + tid] =
      scol4[0][tid] + scol4[1][tid] + scol4[2][tid] + scol4[3][tid];
  if (tid == 0) sqpart[blockIdx.x] = sSl[0] + sSl[1] + sSl[2] + sSl[3];
}

// ---- bw: reduce partials -> bandwidth coefficient c4 ----
__global__ __launch_bounds__(256) void bw_kernel(
    const float* __restrict__ colpart, const float* __restrict__ sqpart,
    float* __restrict__ cf)
{
  __shared__ float red[256];
  const int t = threadIdx.x;
  float cs = 0.f;
  for (int b = 0; b < PREPB; ++b) cs += colpart[b * 256 + t];  // coalesced
  red[t] = cs * cs;
  __syncthreads();
  for (int off = 128; off > 0; off >>= 1) {
    if (t < off) red[t] += red[t + off];
    __syncthreads();
  }
  const float s2 = red[0];
  __syncthreads();
  red[t] = (t < PREPB) ? sqpart[t] : 0.f;
  __syncthreads();
  for (int off = 128; off > 0; off >>= 1) {
    if (t < off) red[t] += red[t + off];
    __syncthreads();
  }
  if (t == 0) {
    const double sumd2 = 2.0 * (double)NTOT * (double)red[0] - 2.0 * (double)s2;
    const double bw = sumd2 / ((double)NTOT * (double)NTOT - (double)NTOT) / 4.0;
    cf[0] = (float)(-1.4426950408889634 / (bw * 16.0));  // c4
  }
}

// ---- main: triangular 128x128 tiles, fp8 MFMA, BK=128 (2 K-tiles, 3 barriers),
//      32 KB single-buffer LDS (4 blk/CU), packed-f32 1-exp epilogue ----
__global__ __launch_bounds__(256) void pair_kernel(
    const unsigned char* __restrict__ xb, const float* __restrict__ sq,
    const float* __restrict__ cf, float* __restrict__ part)
{
  // XCD slab map (bijective, NTRI%8==0): L2 locality per XCD
  const int idx = (blockIdx.x & 7) * (NTRI / 8) + (blockIdx.x >> 3);
  const float rr = sqrtf(4160.25f - 2.0f * (float)idx);
  int bi = (int)(64.5f - rr);
  while (NT * (bi + 1) - (bi + 1) * bi / 2 <= idx) ++bi;
  while (NT * bi - bi * (bi - 1) / 2 > idx) --bi;
  const int bj = bi + (idx - (NT * bi - bi * (bi - 1) / 2));

  __shared__ __align__(16) unsigned char lA[128 * 128];  // 16 KB (BK=128 fp8)
  __shared__ __align__(16) unsigned char lB[128 * 128];  // 16 KB
  __shared__ float sqA[128], sqB[128], wsum[4];

  const int tid = threadIdx.x, wave = tid >> 6, lane = tid & 63;
  const int wr = wave >> 1, wc = wave & 1;

  const float c4 = cf[0];
  if (tid < 128) sqA[tid] = sq[bi * 128 + tid];
  else           sqB[tid - 128] = sq[bj * 128 + (tid - 128)];

  // Staging (rule 21): gload_lds dest is linear (wave base + lane*16); the
  // 16B-slot XOR swizzle LDS[row][s] = G[row][s ^ (row&7)] comes from the
  // pre-swizzled per-lane GLOBAL source slot. row&7 == lane>>3 here.
  const unsigned char* gA0 =
      xb + (size_t)(bi * 128 + wave * 32 + (lane >> 3)) * D + ((lane & 7) ^ (lane >> 3)) * 16;
  const unsigned char* gB0 =
      xb + (size_t)(bj * 128 + wave * 32 + (lane >> 3)) * D + ((lane & 7) ^ (lane >> 3)) * 16;
  char* dA = (char*)lA + wave * 4096;
  char* dB = (char*)lB + wave * 4096;

#define STAGE(t) do {                                                        \
    _Pragma("unroll")                                                        \
    for (int q = 0; q < 4; ++q) {                                            \
      __builtin_amdgcn_global_load_lds(                                      \
          (const GLB_AS uint32_t*)(gA0 + (size_t)q * 8 * D + (t) * 128),     \
          (LDS_AS uint32_t*)(dA + q * 1024), 16, 0, 0);                      \
      __builtin_amdgcn_global_load_lds(                                      \
          (const GLB_AS uint32_t*)(gB0 + (size_t)q * 8 * D + (t) * 128),     \
          (LDS_AS uint32_t*)(dB + q * 1024), 16, 0, 0);                      \
    } } while (0)

  f32x4 acc[4][4];
  #pragma unroll
  for (int mi = 0; mi < 4; ++mi)
    #pragma unroll
    for (int nj = 0; nj < 4; ++nj)
      acc[mi][nj] = (f32x4){0.f, 0.f, 0.f, 0.f};

  // fragment read geometry: row = base + mi*16 + (lane&15); k-byte
  // c = ks*32 + (lane>>4)*8 -> swizzled byte = ((c>>4)^(row&7))<<4 | (c&8)
  const int g = lane >> 4, r7 = lane & 7, rlow = lane & 15;
  const int off8 = (g & 1) * 8, ghalf = g >> 1;

  #pragma unroll
  for (int t = 0; t < 2; ++t) {            // 2 K-tiles of 128
    STAGE(t);
    __syncthreads();                       // drain: tile t resident
    #pragma unroll
    for (int ks = 0; ks < 4; ++ks) {       // K = 4 x 32 within tile
      const int slot = (2 * ks + ghalf);
      long af[4], bf[4];
      #pragma unroll
      for (int mi = 0; mi < 4; ++mi) {
        const int rowA = wr * 64 + mi * 16 + rlow;
        af[mi] = *(const long*)((const char*)lA + rowA * 128 +
                                (((slot ^ r7)) << 4) + off8);
      }
      #pragma unroll
      for (int nj = 0; nj < 4; ++nj) {
        const int rowB = wc * 64 + nj * 16 + rlow;
        bf[nj] = *(const long*)((const char*)lB + rowB * 128 +
                                (((slot ^ r7)) << 4) + off8);
      }
      #pragma unroll
      for (int mi = 0; mi < 4; ++mi)
        #pragma unroll
        for (int nj = 0; nj < 4; ++nj)
          acc[mi][nj] = __builtin_amdgcn_mfma_f32_16x16x32_fp8_fp8(
              af[mi], bf[nj], acc[mi][nj], 0, 0, 0);
    }
    if (t == 0) __syncthreads();           // readers done before overwrite
  }
#undef STAGE

  // epilogue (packed f32 over row-pairs): d2 = si + sj - 2*gram;
  // e4 = exp2(d2*c4); e3=e4^2; e2=e3^2; e1=e2^2; e0=e1^2
  const int r0c = (lane >> 4) * 4, cc = lane & 15;
  const f32x2 c42 = (f32x2){c4, c4};
  const f32x2 n22 = (f32x2){-2.f, -2.f};
  const f32x2 z2  = (f32x2){0.f, 0.f};
  float sjv[4];
  #pragma unroll
  for (int nj = 0; nj < 4; ++nj) sjv[nj] = sqB[wc * 64 + nj * 16 + cc];
  f32x2 tsum2 = z2;
  #pragma unroll
  for (int mi = 0; mi < 4; ++mi) {
    #pragma unroll
    for (int p = 0; p < 2; ++p) {          // row pairs (2p, 2p+1)
      const f32x2 si2 = (f32x2){sqA[wr * 64 + mi * 16 + r0c + 2 * p],
                                sqA[wr * 64 + mi * 16 + r0c + 2 * p + 1]};
      #pragma unroll
      for (int nj = 0; nj < 4; ++nj) {
        const f32x2 a2 = (f32x2){acc[mi][nj][2 * p], acc[mi][nj][2 * p + 1]};
        const f32x2 sj2 = (f32x2){sjv[nj], sjv[nj]};
        f32x2 d2 = __builtin_elementwise_fma(n22, a2, si2 + sj2);  // v_pk_fma
        d2 = __builtin_elementwise_max(d2, z2);                    // v_pk_max
        const f32x2 x2 = d2 * c42;                                 // v_pk_mul
        const f32x2 e4 = (f32x2){EXP2F(x2[0]), EXP2F(x2[1])};
        const f32x2 e3 = e4 * e4, e2v = e3 * e3;
        const f32x2 e1 = e2v * e2v, e0 = e1 * e1;
        tsum2 += ((e4 + e3) + (e2v + e1)) + e0;                    // v_pk_add
      }
    }
  }
  float tsum = tsum2[0] + tsum2[1];
  #pragma unroll
  for (int off = 32; off > 0; off >>= 1) tsum += __shfl_down(tsum, off);
  if (lane == 0) wsum[wave] = tsum;
  __syncthreads();
  if (tid == 0) part[idx] = wsum[0] + wsum[1] + wsum[2] + wsum[3];
}

// ---- out: deterministic tree-reduce of tile partials (1024 threads) ----
__global__ __launch_bounds__(1024) void out_kernel(
    const float* __restrict__ part, float* __restrict__ out)
{
  __shared__ double red0[1024], red1[1024], red2[1024];
  const int t = threadIdx.x;
  double a0 = 0.0, a1 = 0.0, a2 = 0.0;
  for (int j = t; j < NTRI; j += 1024) {
    const float r1 = sqrtf(4160.25f - 2.0f * (float)j);
    int bi = (int)(64.5f - r1);
    while (NT * (bi + 1) - (bi + 1) * bi / 2 <= j) ++bi;
    while (NT * bi - bi * (bi - 1) / 2 > j) --bi;
    const int bj = bi + (j - (NT * bi - bi * (bi - 1) / 2));
    const double w = (bi == bj) ? 1.0 : 2.0;
    const double v = w * (double)part[j];
    if (bi >= 32) a1 += v;
    else if (bj >= 32) a2 += v;
    else a0 += v;
  }
  red0[t] = a0; red1[t] = a1; red2[t] = a2;
  __syncthreads();
  for (int off = 512; off > 0; off >>= 1) {
    if (t < off) {
      red0[t] += red0[t + off];
      red1[t] += red1[t + off];
      red2[t] += red2[t + off];
    }
    __syncthreads();
  }
  if (t == 0)
    out[0] = (float)((red0[0] + red1[0] - red2[0]) /
                     ((double)NSRC * (double)NSRC));
}

extern "C" void kernel_launch(void* const* d_in, const int* in_sizes, int n_in,
                              void* d_out, int out_size, void* d_ws, size_t ws_size,
                              hipStream_t stream) {
  (void)in_sizes; (void)n_in; (void)out_size; (void)ws_size;
  const float* src = (const float*)d_in[0];
  const float* tgt = (const float*)d_in[1];
  char* ws = (char*)d_ws;
  unsigned char* xb = (unsigned char*)(ws + OFF_XB);
  float* sq      = (float*)(ws + OFF_SQ);
  float* colpart = (float*)(ws + OFF_CP);
  float* sqpart  = (float*)(ws + OFF_SP);
  float* cf      = (float*)(ws + OFF_CF);
  float* part    = (float*)(ws + OFF_PT);

  prep_kernel<<<PREPB, 256, 0, stream>>>(src, tgt, xb, sq, colpart, sqpart);
  bw_kernel<<<1, 256, 0, stream>>>(colpart, sqpart, cf);
  pair_kernel<<<NTRI, 256, 0, stream>>>(xb, sq, cf, part);
  out_kernel<<<1, 1024, 0, stream>>>(part, (float*)d_out);
}

// Round 17
// 46.992 us; speedup vs baseline: 1.0491x; 1.0491x over previous
//
#include <hip/hip_runtime.h>
#include <hip/hip_bf16.h>
#include <stdint.h>
#include <math.h>

#define D     256
#define NTOT  8192
#define NSRC  4096
#define NT    64                  // 64 tiles of 128 rows
#define NTRI  (NT * (NT + 1) / 2) // 2080 upper-tri tiles
#define PREPB 256                 // prep blocks (32 rows each)

using f32x4 = __attribute__((ext_vector_type(4))) float;
using f32x2 = __attribute__((ext_vector_type(2))) float;

#define GLB_AS __attribute__((address_space(1)))
#define LDS_AS __attribute__((address_space(3)))

#if __has_builtin(__builtin_amdgcn_exp2f)
#define EXP2F __builtin_amdgcn_exp2f
#else
#define EXP2F exp2f
#endif

// ---- manual OCP e4m3 converters (RNE, FTZ below 2^-7, clamp 448) ----
__device__ inline unsigned char f32_to_e4m3(float v) {
  uint32_t u = __float_as_uint(v);
  uint32_t s = (u >> 24) & 0x80u;
  uint32_t m = u & 0x7FFFFFFFu;
  if (m <= 0x3C000000u) return (unsigned char)s;            // |v| <= 2^-7 -> 0
  if (m <  0x3C800000u) return (unsigned char)(s | 0x08u);  // -> min normal 2^-6
  if (m >= 0x43F00000u) return (unsigned char)(s | 0x7Eu);  // clamp to 448
  uint32_t r = m + 0x0007FFFFu + ((m >> 20) & 1u);          // RNE to 3 mant bits
  uint32_t e = (r >> 23) - 127u + 7u;                       // 1..15
  return (unsigned char)(s | (e << 3) | ((r >> 20) & 7u));
}
__device__ inline float e4m3_to_f32(unsigned char q) {
  uint32_t s = ((uint32_t)(q & 0x80u)) << 24;
  uint32_t em = q & 0x7Fu;
  if (em == 0) return __uint_as_float(s);                   // we never emit denormals
  uint32_t e = (em >> 3) + 120u;                            // -7 + 127
  return __uint_as_float(s | (e << 23) | ((em & 7u) << 20));
}

// Cross-block state for the fused bandwidth reduce (R11-validated pattern,
// prep side only — 256 blocks, NOT the 2080-block pair kernel). 8-sliced
// accumulators cut per-address atomic serialization 8x vs R11. Device
// globals: zero at module load; every launch self-restores via atomicExch
// => identical start state each graph replay, immune to d_ws poisoning.
__device__ float        g_colpart8[8][256];
__device__ float        g_Ssum8[8];
__device__ unsigned int g_cnt0;
__device__ float        g_cf;

// workspace layout (bytes) — every region fully written before read each
// launch (pair/out side has no atomics/fences/counters) => deterministic.
#define OFF_XB   ((size_t)0)                 // 2 MB fp8 X
#define OFF_SQ   ((size_t)NTOT * D)          // 8192 f32 row sq-norms
#define OFF_PT   (OFF_SQ + (size_t)NTOT * 4) // per-tile partials [NTRI]
#define OFF_END  (OFF_PT + (size_t)NTRI * 4)

// ---- prep: f32 -> fp8 roundtrip, row sq-norms; LAST block computes c4 ----
__global__ __launch_bounds__(256) void prep_kernel(
    const float* __restrict__ src, const float* __restrict__ tgt,
    unsigned char* __restrict__ xb, float* __restrict__ sq)
{
  __shared__ float scol4[4][256];
  __shared__ float sSl[4];
  __shared__ int slast;
  const int tid = threadIdx.x, wave = tid >> 6, lane = tid & 63;
  const int row0 = blockIdx.x * 32 + wave * 8;     // blocks never straddle sides
  const float* p0 = (row0 < NSRC) ? (src + (size_t)row0 * D)
                                  : (tgt + (size_t)(row0 - NSRC) * D);
  float c0 = 0.f, c1 = 0.f, c2 = 0.f, c3 = 0.f, swave = 0.f;
  for (int rr = 0; rr < 8; ++rr) {
    const int row = row0 + rr;
    const float4 v = reinterpret_cast<const float4*>(p0 + (size_t)rr * D)[lane];
    uchar4 h;
    h.x = f32_to_e4m3(v.x); h.y = f32_to_e4m3(v.y);
    h.z = f32_to_e4m3(v.z); h.w = f32_to_e4m3(v.w);
    reinterpret_cast<uchar4*>(xb + (size_t)row * D)[lane] = h;
    const float f0 = e4m3_to_f32(h.x), f1 = e4m3_to_f32(h.y),
                f2 = e4m3_to_f32(h.z), f3 = e4m3_to_f32(h.w);
    c0 += f0; c1 += f1; c2 += f2; c3 += f3;
    float s = f0 * f0 + f1 * f1 + f2 * f2 + f3 * f3;
    #pragma unroll
    for (int off = 32; off > 0; off >>= 1) s += __shfl_down(s, off);
    if (lane == 0) { sq[row] = s; swave += s; }
  }
  scol4[wave][lane * 4 + 0] = c0;
  scol4[wave][lane * 4 + 1] = c1;
  scol4[wave][lane * 4 + 2] = c2;
  scol4[wave][lane * 4 + 3] = c3;
  if (lane == 0) sSl[wave] = swave;
  __syncthreads();
  // 8-sliced device accumulation: 32 blocks/slice -> 32 RMWs/address (~0.6us)
  atomicAdd(&g_colpart8[blockIdx.x & 7][tid],
            scol4[0][tid] + scol4[1][tid] + scol4[2][tid] + scol4[3][tid]);
  if (tid == 0) {
    atomicAdd(&g_Ssum8[blockIdx.x & 7], sSl[0] + sSl[1] + sSl[2] + sSl[3]);
    __threadfence();   // release: this block's adds visible device-wide
    slast = (atomicAdd(&g_cnt0, 1u) == (unsigned)(PREPB - 1));
  }
  __syncthreads();
  if (slast) {
    float cs = 0.f;
    #pragma unroll
    for (int s = 0; s < 8; ++s)
      cs += atomicExch(&g_colpart8[s][tid], 0.f);  // coherent read + reset
    scol4[0][tid] = cs * cs;
    __syncthreads();
    for (int off = 128; off > 0; off >>= 1) {
      if (tid < off) scol4[0][tid] += scol4[0][tid + off];
      __syncthreads();
    }
    if (tid == 0) {
      float S = 0.f;
      #pragma unroll
      for (int s = 0; s < 8; ++s) S += atomicExch(&g_Ssum8[s], 0.f);
      atomicExch(&g_cnt0, 0u);                     // restore for replay
      const double sumd2 = 2.0 * (double)NTOT * (double)S
                         - 2.0 * (double)scol4[0][0];
      const double bw = sumd2 / ((double)NTOT * (double)NTOT - (double)NTOT) / 4.0;
      g_cf = (float)(-1.4426950408889634 / (bw * 16.0)); // c4
    }
  }
}

// ---- main: triangular 128x128 tiles, fp8 MFMA, BK=128 (2 K-tiles, 3 barriers),
//      32 KB single-buffer LDS (4 blk/CU), packed-f32 1-exp epilogue ----
__global__ __launch_bounds__(256) void pair_kernel(
    const unsigned char* __restrict__ xb, const float* __restrict__ sq,
    float* __restrict__ part)
{
  // XCD slab map (bijective, NTRI%8==0): L2 locality per XCD
  const int idx = (blockIdx.x & 7) * (NTRI / 8) + (blockIdx.x >> 3);
  const float rr = sqrtf(4160.25f - 2.0f * (float)idx);
  int bi = (int)(64.5f - rr);
  while (NT * (bi + 1) - (bi + 1) * bi / 2 <= idx) ++bi;
  while (NT * bi - bi * (bi - 1) / 2 > idx) --bi;
  const int bj = bi + (idx - (NT * bi - bi * (bi - 1) / 2));

  __shared__ __align__(16) unsigned char lA[128 * 128];  // 16 KB (BK=128 fp8)
  __shared__ __align__(16) unsigned char lB[128 * 128];  // 16 KB
  __shared__ float sqA[128], sqB[128], wsum[4];

  const int tid = threadIdx.x, wave = tid >> 6, lane = tid & 63;
  const int wr = wave >> 1, wc = wave & 1;

  const float c4 = g_cf;   // written by prep's last block (kernel-boundary ordered)
  if (tid < 128) sqA[tid] = sq[bi * 128 + tid];
  else           sqB[tid - 128] = sq[bj * 128 + (tid - 128)];

  // Staging (rule 21): gload_lds dest is linear (wave base + lane*16); the
  // 16B-slot XOR swizzle LDS[row][s] = G[row][s ^ (row&7)] comes from the
  // pre-swizzled per-lane GLOBAL source slot. row&7 == lane>>3 here.
  const unsigned char* gA0 =
      xb + (size_t)(bi * 128 + wave * 32 + (lane >> 3)) * D + ((lane & 7) ^ (lane >> 3)) * 16;
  const unsigned char* gB0 =
      xb + (size_t)(bj * 128 + wave * 32 + (lane >> 3)) * D + ((lane & 7) ^ (lane >> 3)) * 16;
  char* dA = (char*)lA + wave * 4096;
  char* dB = (char*)lB + wave * 4096;

#define STAGE(t) do {                                                        \
    _Pragma("unroll")                                                        \
    for (int q = 0; q < 4; ++q) {                                            \
      __builtin_amdgcn_global_load_lds(                                      \
          (const GLB_AS uint32_t*)(gA0 + (size_t)q * 8 * D + (t) * 128),     \
          (LDS_AS uint32_t*)(dA + q * 1024), 16, 0, 0);                      \
      __builtin_amdgcn_global_load_lds(                                      \
          (const GLB_AS uint32_t*)(gB0 + (size_t)q * 8 * D + (t) * 128),     \
          (LDS_AS uint32_t*)(dB + q * 1024), 16, 0, 0);                      \
    } } while (0)

  f32x4 acc[4][4];
  #pragma unroll
  for (int mi = 0; mi < 4; ++mi)
    #pragma unroll
    for (int nj = 0; nj < 4; ++nj)
      acc[mi][nj] = (f32x4){0.f, 0.f, 0.f, 0.f};

  // fragment read geometry: row = base + mi*16 + (lane&15); k-byte
  // c = ks*32 + (lane>>4)*8 -> swizzled byte = ((c>>4)^(row&7))<<4 | (c&8)
  const int g = lane >> 4, r7 = lane & 7, rlow = lane & 15;
  const int off8 = (g & 1) * 8, ghalf = g >> 1;

  #pragma unroll
  for (int t = 0; t < 2; ++t) {            // 2 K-tiles of 128
    STAGE(t);
    __syncthreads();                       // drain: tile t resident
    #pragma unroll
    for (int ks = 0; ks < 4; ++ks) {       // K = 4 x 32 within tile
      const int slot = (2 * ks + ghalf);
      long af[4], bf[4];
      #pragma unroll
      for (int mi = 0; mi < 4; ++mi) {
        const int rowA = wr * 64 + mi * 16 + rlow;
        af[mi] = *(const long*)((const char*)lA + rowA * 128 +
                                (((slot ^ r7)) << 4) + off8);
      }
      #pragma unroll
      for (int nj = 0; nj < 4; ++nj) {
        const int rowB = wc * 64 + nj * 16 + rlow;
        bf[nj] = *(const long*)((const char*)lB + rowB * 128 +
                                (((slot ^ r7)) << 4) + off8);
      }
      #pragma unroll
      for (int mi = 0; mi < 4; ++mi)
        #pragma unroll
        for (int nj = 0; nj < 4; ++nj)
          acc[mi][nj] = __builtin_amdgcn_mfma_f32_16x16x32_fp8_fp8(
              af[mi], bf[nj], acc[mi][nj], 0, 0, 0);
    }
    if (t == 0) __syncthreads();           // readers done before overwrite
  }
#undef STAGE

  // epilogue (packed f32 over row-pairs): d2 = si + sj - 2*gram;
  // e4 = exp2(d2*c4); e3=e4^2; e2=e3^2; e1=e2^2; e0=e1^2
  const int r0c = (lane >> 4) * 4, cc = lane & 15;
  const f32x2 c42 = (f32x2){c4, c4};
  const f32x2 n22 = (f32x2){-2.f, -2.f};
  const f32x2 z2  = (f32x2){0.f, 0.f};
  float sjv[4];
  #pragma unroll
  for (int nj = 0; nj < 4; ++nj) sjv[nj] = sqB[wc * 64 + nj * 16 + cc];
  f32x2 tsum2 = z2;
  #pragma unroll
  for (int mi = 0; mi < 4; ++mi) {
    #pragma unroll
    for (int p = 0; p < 2; ++p) {          // row pairs (2p, 2p+1)
      const f32x2 si2 = (f32x2){sqA[wr * 64 + mi * 16 + r0c + 2 * p],
                                sqA[wr * 64 + mi * 16 + r0c + 2 * p + 1]};
      #pragma unroll
      for (int nj = 0; nj < 4; ++nj) {
        const f32x2 a2 = (f32x2){acc[mi][nj][2 * p], acc[mi][nj][2 * p + 1]};
        const f32x2 sj2 = (f32x2){sjv[nj], sjv[nj]};
        f32x2 d2 = __builtin_elementwise_fma(n22, a2, si2 + sj2);  // v_pk_fma
        d2 = __builtin_elementwise_max(d2, z2);                    // v_pk_max
        const f32x2 x2 = d2 * c42;                                 // v_pk_mul
        const f32x2 e4 = (f32x2){EXP2F(x2[0]), EXP2F(x2[1])};
        const f32x2 e3 = e4 * e4, e2v = e3 * e3;
        const f32x2 e1 = e2v * e2v, e0 = e1 * e1;
        tsum2 += ((e4 + e3) + (e2v + e1)) + e0;                    // v_pk_add
      }
    }
  }
  float tsum = tsum2[0] + tsum2[1];
  #pragma unroll
  for (int off = 32; off > 0; off >>= 1) tsum += __shfl_down(tsum, off);
  if (lane == 0) wsum[wave] = tsum;
  __syncthreads();
  if (tid == 0) part[idx] = wsum[0] + wsum[1] + wsum[2] + wsum[3];
}

// ---- out: deterministic tree-reduce of tile partials (1024 threads) ----
__global__ __launch_bounds__(1024) void out_kernel(
    const float* __restrict__ part, float* __restrict__ out)
{
  __shared__ double red0[1024], red1[1024], red2[1024];
  const int t = threadIdx.x;
  double a0 = 0.0, a1 = 0.0, a2 = 0.0;
  for (int j = t; j < NTRI; j += 1024) {
    const float r1 = sqrtf(4160.25f - 2.0f * (float)j);
    int bi = (int)(64.5f - r1);
    while (NT * (bi + 1) - (bi + 1) * bi / 2 <= j) ++bi;
    while (NT * bi - bi * (bi - 1) / 2 > j) --bi;
    const int bj = bi + (j - (NT * bi - bi * (bi - 1) / 2));
    const double w = (bi == bj) ? 1.0 : 2.0;
    const double v = w * (double)part[j];
    if (bi >= 32) a1 += v;
    else if (bj >= 32) a2 += v;
    else a0 += v;
  }
  red0[t] = a0; red1[t] = a1; red2[t] = a2;
  __syncthreads();
  for (int off = 512; off > 0; off >>= 1) {
    if (t < off) {
      red0[t] += red0[t + off];
      red1[t] += red1[t + off];
      red2[t] += red2[t + off];
    }
    __syncthreads();
  }
  if (t == 0)
    out[0] = (float)((red0[0] + red1[0] - red2[0]) /
                     ((double)NSRC * (double)NSRC));
}

extern "C" void kernel_launch(void* const* d_in, const int* in_sizes, int n_in,
                              void* d_out, int out_size, void* d_ws, size_t ws_size,
                              hipStream_t stream) {
  (void)in_sizes; (void)n_in; (void)out_size; (void)ws_size;
  const float* src = (const float*)d_in[0];
  const float* tgt = (const float*)d_in[1];
  char* ws = (char*)d_ws;
  unsigned char* xb = (unsigned char*)(ws + OFF_XB);
  float* sq   = (float*)(ws + OFF_SQ);
  float* part = (float*)(ws + OFF_PT);

  prep_kernel<<<PREPB, 256, 0, stream>>>(src, tgt, xb, sq);
  pair_kernel<<<NTRI, 256, 0, stream>>>(xb, sq, part);
  out_kernel<<<1, 1024, 0, stream>>>(part, (float*)d_out);
}